// Round 4
// baseline (1041.088 us; speedup 1.0000x reference)
//
#include <hip/hip_runtime.h>
#include <hip/hip_bf16.h>

// BinaryLinear: out = x @ sign(W)^T
// x: [32,4096,1024] f32 -> A [M=131072][K=1024]
// W: [1024,1024] f32    -> B^T = sign(W) [N=1024][K=1024] bf16 in d_ws (once)
// out: [M][N] f32
//
// R4 vs R2 (557us, MfmaUtil 21%; LDS pipe ~850cy/step vs MFMA ~620cy => LDS-bound):
//  B fragments read DIRECTLY from L2 (Bs is 2MiB, L2-resident) via
//  global_load_dwordx4 -- no LDS staging for B at all. Removes 2/3 of LDS
//  traffic + the gll barrier drain. A staging identical to R2 (verified order,
//  keeps VGPR ~116 -- R3's T14 split cliffed occupancy and regressed).

typedef __attribute__((ext_vector_type(8))) short bf16x8;
typedef __attribute__((ext_vector_type(4))) float f32x4;

#define BM 128
#define BN 256
#define BK 32
#define KDIM 1024
#define NDIM 1024
#define NKSTEP (KDIM / BK)
#define PADA 40  // ushorts per sA row: 32 data + 8 pad => 80-byte rows

__device__ __forceinline__ unsigned cvt2(float a, float b) {
  unsigned r;
  asm("v_cvt_pk_bf16_f32 %0, %1, %2" : "=v"(r) : "v"(a), "v"(b));
  return r;
}

// ---- pre-kernel: Bs[n][k] = sign(W[n][k]) as bf16 (+1, -1, or 0) ----
__global__ void sign_kernel(const float4* __restrict__ W, ushort4* __restrict__ Bs, int n4) {
  int i = blockIdx.x * blockDim.x + threadIdx.x;
  if (i >= n4) return;
  float4 v = W[i];
  const float* pv = (const float*)&v;
  ushort4 r;
  unsigned short* pr = (unsigned short*)&r;
#pragma unroll
  for (int j = 0; j < 4; ++j) {
    union { float f; unsigned int u; } c; c.f = pv[j];
    pr[j] = ((c.u & 0x7fffffffu) == 0u)
                ? (unsigned short)0
                : (unsigned short)(0x3f80u | ((c.u >> 16) & 0x8000u));
  }
  Bs[i] = r;
}

// ---- main GEMM ----
__global__ __launch_bounds__(256) void bgemm_kernel(
    const float* __restrict__ X,
    const unsigned short* __restrict__ Bs,
    float* __restrict__ O) {
  __shared__ unsigned short sA[2][BM * PADA];  // 2 x 10240 B = 20 KB total

  const int t = threadIdx.x;
  const int l = t & 63;
  const int w = t >> 6;
  const int wr = w >> 1;
  const int wc = w & 1;

  // XCD-bijective swizzle: 4 N-tiles of one M-tile adjacent on the SAME XCD.
  const unsigned nwg = gridDim.x;
  unsigned swz = blockIdx.x;
  if ((nwg & 7u) == 0u) swz = (blockIdx.x & 7u) * (nwg >> 3) + (blockIdx.x >> 3);
  const int bm = (int)(swz >> 2);
  const int bn = (int)(swz & 3u);
  const size_t m0 = (size_t)bm * BM;
  const int N0 = bn * BN;

  // A staging: thread t owns row r = t>>1, k-half h = (t&1)*16 (16 contiguous floats)
  const int ar = t >> 1;
  const int ah = (t & 1) * 16;
  const float* ag = X + (m0 + (size_t)ar) * KDIM + ah;
  const int aw = ar * PADA + ah;

  // B: direct-from-L2 fragment pointers. Lane l reads row n = N0+wc*128+j*16+(l&15),
  // k-chunk kb = l>>4 (8 bf16 = 16B). Per wave-load: 16 rows x 64B full lines.
  const int ll = l & 15;
  const int kb = l >> 4;
  const unsigned short* bp[8];
#pragma unroll
  for (int j = 0; j < 8; ++j) {
    int n = N0 + wc * 128 + j * 16 + ll;
    bp[j] = Bs + (size_t)n * KDIM + kb * 8;
  }

  // A fragment read offsets (LDS)
  int offA[4];
#pragma unroll
  for (int i = 0; i < 4; ++i)
    offA[i] = (wr * 64 + i * 16 + ll) * PADA + kb * 8;

  f32x4 acc[4][8];
#pragma unroll
  for (int i = 0; i < 4; ++i)
#pragma unroll
    for (int j = 0; j < 8; ++j) acc[i][j] = (f32x4)0.0f;

  // prologue: stage A tile 0 into buf 0
  {
    const float4* ap = reinterpret_cast<const float4*>(ag);
    float4 v0 = ap[0], v1 = ap[1], v2 = ap[2], v3 = ap[3];
    uint4 lo, hi;
    lo.x = cvt2(v0.x, v0.y); lo.y = cvt2(v0.z, v0.w);
    lo.z = cvt2(v1.x, v1.y); lo.w = cvt2(v1.z, v1.w);
    hi.x = cvt2(v2.x, v2.y); hi.y = cvt2(v2.z, v2.w);
    hi.z = cvt2(v3.x, v3.y); hi.w = cvt2(v3.z, v3.w);
    *reinterpret_cast<uint4*>(&sA[0][aw]) = lo;
    *reinterpret_cast<uint4*>(&sA[0][aw + 8]) = hi;
  }
  __syncthreads();

#define STEP(CUR)                                                              \
  {                                                                            \
    const int kof = kk * BK;                                                   \
    bf16x8 bv[8];                                                              \
    _Pragma("unroll") for (int j = 0; j < 8; ++j)                              \
        bv[j] = *reinterpret_cast<const bf16x8*>(bp[j] + kof);                 \
    if (kk + 1 < NKSTEP) {                                                     \
      const float4* ap = reinterpret_cast<const float4*>(ag + (kk + 1) * BK);  \
      float4 v0 = ap[0], v1 = ap[1], v2 = ap[2], v3 = ap[3];                   \
      uint4 lo, hi;                                                            \
      lo.x = cvt2(v0.x, v0.y); lo.y = cvt2(v0.z, v0.w);                        \
      lo.z = cvt2(v1.x, v1.y); lo.w = cvt2(v1.z, v1.w);                        \
      hi.x = cvt2(v2.x, v2.y); hi.y = cvt2(v2.z, v2.w);                        \
      hi.z = cvt2(v3.x, v3.y); hi.w = cvt2(v3.z, v3.w);                        \
      *reinterpret_cast<uint4*>(&sA[(CUR) ^ 1][aw]) = lo;                      \
      *reinterpret_cast<uint4*>(&sA[(CUR) ^ 1][aw + 8]) = hi;                  \
    }                                                                          \
    const unsigned short* sa = sA[CUR];                                        \
    bf16x8 av[4];                                                              \
    _Pragma("unroll") for (int i = 0; i < 4; ++i)                              \
        av[i] = *reinterpret_cast<const bf16x8*>(sa + offA[i]);                \
    _Pragma("unroll") for (int i = 0; i < 4; ++i)                              \
        _Pragma("unroll") for (int j = 0; j < 8; ++j)                          \
            acc[i][j] = __builtin_amdgcn_mfma_f32_16x16x32_bf16(               \
                av[i], bv[j], acc[i][j], 0, 0, 0);                             \
    __syncthreads();                                                           \
    ++kk;                                                                      \
  }

  int kk = 0;
  while (kk < NKSTEP) {
    STEP(0)
    STEP(1)
  }
#undef STEP

  // epilogue: C/D layout col = lane&15, row = (lane>>4)*4 + reg
  const int crow = (l >> 4) * 4;
#pragma unroll
  for (int i = 0; i < 4; ++i) {
    const size_t r0 = m0 + wr * 64 + i * 16 + crow;
#pragma unroll
    for (int j = 0; j < 8; ++j) {
      const int col = N0 + wc * 128 + j * 16 + ll;
      float* op = O + r0 * NDIM + col;
#pragma unroll
      for (int e = 0; e < 4; ++e) op[(size_t)e * NDIM] = acc[i][j][e];
    }
  }
}

// ---- fallback (only if ws too small for the 2 MiB sign buffer) ----
__global__ void naive_kernel(const float* __restrict__ X, const float* __restrict__ W,
                             float* __restrict__ O, long long total) {
  long long idx = (long long)blockIdx.x * blockDim.x + threadIdx.x;
  if (idx >= total) return;
  int n = (int)(idx & (NDIM - 1));
  long long m = idx >> 10;
  const float* xr = X + m * KDIM;
  const float* wr = W + (long long)n * KDIM;
  float s = 0.f;
  for (int k = 0; k < KDIM; ++k) {
    float wv = wr[k];
    float sg = (wv > 0.f) ? 1.f : ((wv < 0.f) ? -1.f : 0.f);
    s += xr[k] * sg;
  }
  O[idx] = s;
}

extern "C" void kernel_launch(void* const* d_in, const int* in_sizes, int n_in,
                              void* d_out, int out_size, void* d_ws, size_t ws_size,
                              hipStream_t stream) {
  const float* X = (const float*)d_in[0];
  const float* W = (const float*)d_in[1];
  float* O = (float*)d_out;
  const long long M = (long long)in_sizes[0] / KDIM;  // 131072

  const size_t need_ws = (size_t)NDIM * KDIM * sizeof(unsigned short);  // 2 MiB
  if (ws_size >= need_ws && (M % BM) == 0) {
    unsigned short* Bs = (unsigned short*)d_ws;
    int n4 = (NDIM * KDIM) / 4;
    sign_kernel<<<dim3(n4 / 256), dim3(256), 0, stream>>>(
        (const float4*)W, (ushort4*)Bs, n4);
    dim3 grid((unsigned)((M / BM) * (NDIM / BN)));
    bgemm_kernel<<<grid, dim3(256), 0, stream>>>(X, Bs, O);
  } else {
    long long total = M * NDIM;
    long long blocks = (total + 255) / 256;
    naive_kernel<<<dim3((unsigned)blocks), dim3(256), 0, stream>>>(X, W, O, total);
  }
}

// Round 6
// 429.145 us; speedup vs baseline: 2.4260x; 2.4260x over previous
//
#include <hip/hip_runtime.h>
#include <hip/hip_bf16.h>

// BinaryLinear: out = x @ sign(W)^T
// x: [32,4096,1024] f32 -> A [M=131072][K=1024]
// W: [1024,1024] f32    -> B^T = sign(W) [N=1024][K=1024] bf16 in d_ws (once)
// out: [M][N] f32
//
// R6: R5 raced post-timing (1-barrier dbuf + gll visibility). Retreat to the
// provably race-free m97 shape: SINGLE LDS buffer, TWO barriers per K-step:
//   stage-issue -> s_waitcnt vmcnt(0) (explicit) -> barrier -> ds_read+cvt+MFMA -> barrier
// Overlap comes from 3 blocks/CU TLP, not in-wave pipelining (m103: implicit
// wave-level overlap captures the dbuf gain anyway).
// BK=64 (16 steps, 32 MFMA/step). A staged raw f32 via global_load_lds with
// 16-slot XOR swizzle; cvt_pk_bf16 after the LDS read. B 8-slot XOR swizzle
// (2-way bank aliasing = free; R2's 4-slot was 4-way -> 16.8M conflicts).

typedef __attribute__((ext_vector_type(8))) short bf16x8;
typedef __attribute__((ext_vector_type(4))) float f32x4;

#define BM 128
#define BN 128
#define BK 64
#define KDIM 1024
#define NDIM 1024
#define NKSTEP (KDIM / BK)

__device__ __forceinline__ unsigned cvt2(float a, float b) {
  unsigned r;
  asm("v_cvt_pk_bf16_f32 %0, %1, %2" : "=v"(r) : "v"(a), "v"(b));
  return r;
}

// ---- pre-kernel: Bs[n][k] = sign(W[n][k]) as bf16 (+1, -1, or 0) ----
__global__ void sign_kernel(const float4* __restrict__ W, ushort4* __restrict__ Bs, int n4) {
  int i = blockIdx.x * blockDim.x + threadIdx.x;
  if (i >= n4) return;
  float4 v = W[i];
  const float* pv = (const float*)&v;
  ushort4 r;
  unsigned short* pr = (unsigned short*)&r;
#pragma unroll
  for (int j = 0; j < 4; ++j) {
    union { float f; unsigned int u; } c; c.f = pv[j];
    pr[j] = ((c.u & 0x7fffffffu) == 0u)
                ? (unsigned short)0
                : (unsigned short)(0x3f80u | ((c.u >> 16) & 0x8000u));
  }
  Bs[i] = r;
}

// ---- main GEMM ----
__global__ __launch_bounds__(256, 3) void bgemm_kernel(
    const float* __restrict__ X,
    const unsigned short* __restrict__ Bs,
    float* __restrict__ O) {
  // A tile: 128 rows x 16 f32x4-chunks (XOR-swizzled within row) = 32 KB
  // B tile: 128 rows x 8 16B-chunks  (XOR-swizzled within row) = 16 KB
  __shared__ f32x4 sA[BM * 16];
  __shared__ unsigned short sB[BN * BK];

  const int t = threadIdx.x;
  const int l = t & 63;
  const int w = t >> 6;
  const int wr = w >> 1;  // 2x2 wave grid, wave tile 64x64
  const int wc = w & 1;

  // XCD-bijective swizzle; bn fastest => 8 N-sharers of an M-tile on one XCD.
  const unsigned nwg = gridDim.x;
  unsigned swz = blockIdx.x;
  if ((nwg & 7u) == 0u) swz = (blockIdx.x & 7u) * (nwg >> 3) + (blockIdx.x >> 3);
  const int bm = (int)(swz >> 3);
  const int bn = (int)(swz & 7u);
  const size_t m0 = (size_t)bm * BM;
  const int N0 = bn * BN;

  // A staging: 128x64 f32 = 2048 chunks, 8 gll/thread.
  // LDS chunk c = r*16 + s holds global k-chunk q = s ^ (r&15).
  const float* agp[8];
#pragma unroll
  for (int i = 0; i < 8; ++i) {
    int c = i * 256 + t;
    int r = c >> 4;
    int q = (c & 15) ^ (r & 15);
    agp[i] = X + (m0 + (size_t)r) * KDIM + q * 4;
  }

  // B staging: 128x64 bf16 = 1024 chunks, 4 gll/thread.
  // LDS chunk c = n*8 + s holds global k-octet q = s ^ (n&7).
  const unsigned short* bgp[4];
#pragma unroll
  for (int i = 0; i < 4; ++i) {
    int c = i * 256 + t;
    int n = c >> 3;
    int q = (c & 7) ^ (n & 7);
    bgp[i] = Bs + (size_t)(N0 + n) * KDIM + q * 8;
  }

  // fragment read offsets (2 k-subs of 32 per BK=64 step)
  const int ll = l & 15;
  const int kb = l >> 4;
  int idxA[2][4];  // f32x4-chunk index of low half; high = ^1
  int offB[2][4];  // ushort offset
#pragma unroll
  for (int ks = 0; ks < 2; ++ks) {
#pragma unroll
    for (int i = 0; i < 4; ++i) {
      int row = wr * 64 + i * 16 + ll;
      idxA[ks][i] = row * 16 + ((ks * 8 + kb * 2) ^ (row & 15));
    }
#pragma unroll
    for (int j = 0; j < 4; ++j) {
      int n = wc * 64 + j * 16 + ll;
      offB[ks][j] = n * 64 + (((ks * 4 + kb) ^ (n & 7)) * 8);
    }
  }

  f32x4 acc[4][4];
#pragma unroll
  for (int i = 0; i < 4; ++i)
#pragma unroll
    for (int j = 0; j < 4; ++j) acc[i][j] = (f32x4)0.0f;

  for (int kk = 0; kk < NKSTEP; ++kk) {
    const int k0 = kk * BK;
    // ---- stage (single buffer) ----
#pragma unroll
    for (int i = 0; i < 8; ++i)
      __builtin_amdgcn_global_load_lds(
          (const __attribute__((address_space(1))) void*)(agp[i] + k0),
          (__attribute__((address_space(3))) void*)(&sA[i * 256 + t]), 16, 0, 0);
#pragma unroll
    for (int i = 0; i < 4; ++i)
      __builtin_amdgcn_global_load_lds(
          (const __attribute__((address_space(1))) void*)(bgp[i] + k0),
          (__attribute__((address_space(3))) void*)(&sB[(i * 256 + t) * 8]), 16, 0, 0);
    // explicit drain: this wave's gll data must be IN LDS before anyone
    // crosses the barrier (belt-and-braces vs R5's race)
    asm volatile("s_waitcnt vmcnt(0) lgkmcnt(0)" ::: "memory");
    __syncthreads();

    // ---- compute: 2 k-subs x 16 MFMA ----
#pragma unroll
    for (int ks = 0; ks < 2; ++ks) {
      bf16x8 bv[4];
#pragma unroll
      for (int j = 0; j < 4; ++j)
        bv[j] = *reinterpret_cast<const bf16x8*>(sB + offB[ks][j]);
      bf16x8 av[4];
#pragma unroll
      for (int i = 0; i < 4; ++i) {
        f32x4 c0 = sA[idxA[ks][i]];
        f32x4 c1 = sA[idxA[ks][i] ^ 1];
        union { uint4 u; bf16x8 v; } cv;
        cv.u.x = cvt2(c0.x, c0.y); cv.u.y = cvt2(c0.z, c0.w);
        cv.u.z = cvt2(c1.x, c1.y); cv.u.w = cvt2(c1.z, c1.w);
        av[i] = cv.v;
      }
#pragma unroll
      for (int i = 0; i < 4; ++i)
#pragma unroll
        for (int j = 0; j < 4; ++j)
          acc[i][j] = __builtin_amdgcn_mfma_f32_16x16x32_bf16(
              av[i], bv[j], acc[i][j], 0, 0, 0);
    }
    __syncthreads();  // all reads done before next step's stage overwrites
  }

  // epilogue: C/D layout col = lane&15, row = (lane>>4)*4 + reg
  const int crow = kb * 4;
#pragma unroll
  for (int i = 0; i < 4; ++i) {
    const size_t r0 = m0 + wr * 64 + i * 16 + crow;
#pragma unroll
    for (int j = 0; j < 4; ++j) {
      const int col = N0 + wc * 64 + j * 16 + ll;
      float* op = O + r0 * NDIM + col;
#pragma unroll
      for (int e = 0; e < 4; ++e) op[(size_t)e * NDIM] = acc[i][j][e];
    }
  }
}

// ---- fallback (only if ws too small for the 2 MiB sign buffer) ----
__global__ void naive_kernel(const float* __restrict__ X, const float* __restrict__ W,
                             float* __restrict__ O, long long total) {
  long long idx = (long long)blockIdx.x * blockDim.x + threadIdx.x;
  if (idx >= total) return;
  int n = (int)(idx & (NDIM - 1));
  long long m = idx >> 10;
  const float* xr = X + m * KDIM;
  const float* wr = W + (long long)n * KDIM;
  float s = 0.f;
  for (int k = 0; k < KDIM; ++k) {
    float wv = wr[k];
    float sg = (wv > 0.f) ? 1.f : ((wv < 0.f) ? -1.f : 0.f);
    s += xr[k] * sg;
  }
  O[idx] = s;
}

extern "C" void kernel_launch(void* const* d_in, const int* in_sizes, int n_in,
                              void* d_out, int out_size, void* d_ws, size_t ws_size,
                              hipStream_t stream) {
  const float* X = (const float*)d_in[0];
  const float* W = (const float*)d_in[1];
  float* O = (float*)d_out;
  const long long M = (long long)in_sizes[0] / KDIM;  // 131072

  const size_t need_ws = (size_t)NDIM * KDIM * sizeof(unsigned short);  // 2 MiB
  if (ws_size >= need_ws && (M % BM) == 0) {
    unsigned short* Bs = (unsigned short*)d_ws;
    int n4 = (NDIM * KDIM) / 4;
    sign_kernel<<<dim3(n4 / 256), dim3(256), 0, stream>>>(
        (const float4*)W, (ushort4*)Bs, n4);
    dim3 grid((unsigned)((M / BM) * (NDIM / BN)));  // 8192
    bgemm_kernel<<<grid, dim3(256), 0, stream>>>(X, Bs, O);
  } else {
    long long total = M * NDIM;
    long long blocks = (total + 255) / 256;
    naive_kernel<<<dim3((unsigned)blocks), dim3(256), 0, stream>>>(X, W, O, total);
  }
}